// Round 1
// 2236.865 us; speedup vs baseline: 1.6794x; 1.6794x over previous
//
#include <hip/hip_runtime.h>
#include <hip/hip_bf16.h>
#include <math.h>

typedef __hip_bfloat16 bf16;
typedef __bf16 bf16x8 __attribute__((ext_vector_type(8)));
typedef float f32x4 __attribute__((ext_vector_type(4)));

#define VOCAB 32000
#define DE 1024
#define NH 16
#define HD 64
#define NL 4
#define TSEQ 2048
#define MR 4096          // B*T rows
#define WTH_F 128.0f
#define PI_F 3.14159265358979f

__device__ __forceinline__ float wsum(float x) {
  x += __shfl_xor(x, 1);  x += __shfl_xor(x, 2);  x += __shfl_xor(x, 4);
  x += __shfl_xor(x, 8);  x += __shfl_xor(x, 16); x += __shfl_xor(x, 32);
  return x;
}

__device__ __forceinline__ void async16(const bf16* g, bf16* l) {
  __builtin_amdgcn_global_load_lds(
      (const __attribute__((address_space(1))) void*)g,
      (__attribute__((address_space(3))) void*)l, 16, 0, 0);
}

// dual-dtype element read: bf=1 -> bf16, bf=0 -> fp32
__device__ __forceinline__ float rdv(const void* p, size_t i, int bf) {
  return bf ? (float)((const bf16*)p)[i] : ((const float*)p)[i];
}

// ---- cheap 64-lane butterfly primitives ----
// xor1/xor2 via DPP quad_perm (VALU-only), xor4/8/16 via ds_swizzle, xor32 via shfl
template<int CTRL>
__device__ __forceinline__ float dpp_qp(float x) {
  return __int_as_float(__builtin_amdgcn_update_dpp(
      0, __float_as_int(x), CTRL, 0xF, 0xF, false));
}
template<int PAT>
__device__ __forceinline__ float swz(float x) {
  return __int_as_float(__builtin_amdgcn_ds_swizzle(__float_as_int(x), PAT));
}

__device__ __forceinline__ float red1(float a) {
  a += dpp_qp<0xB1>(a);      // xor 1  (quad_perm [1,0,3,2])
  a += dpp_qp<0x4E>(a);      // xor 2  (quad_perm [2,3,0,1])
  a += swz<0x101F>(a);       // xor 4
  a += swz<0x201F>(a);       // xor 8
  a += swz<0x401F>(a);       // xor 16
  a += __shfl_xor(a, 32);    // xor 32
  return a;
}

__device__ __forceinline__ void red4(float& a, float& b, float& c, float& d) {
  a += dpp_qp<0xB1>(a); b += dpp_qp<0xB1>(b); c += dpp_qp<0xB1>(c); d += dpp_qp<0xB1>(d);
  a += dpp_qp<0x4E>(a); b += dpp_qp<0x4E>(b); c += dpp_qp<0x4E>(c); d += dpp_qp<0x4E>(d);
  a += swz<0x101F>(a);  b += swz<0x101F>(b);  c += swz<0x101F>(c);  d += swz<0x101F>(d);
  a += swz<0x201F>(a);  b += swz<0x201F>(b);  c += swz<0x201F>(c);  d += swz<0x201F>(d);
  a += swz<0x401F>(a);  b += swz<0x401F>(b);  c += swz<0x401F>(c);  d += swz<0x401F>(d);
  a += __shfl_xor(a, 32); b += __shfl_xor(b, 32); c += __shfl_xor(c, 32); d += __shfl_xor(d, 32);
}

// ---------------- detect input dtype from embed row 0 ----------------
__global__ __launch_bounds__(256) void detect_kernel(const void* __restrict__ embed,
                                                     int* __restrict__ flag) {
  float ss = 0.f;
#pragma unroll
  for (int i = 0; i < 4; ++i) {
    const float t = (float)((const bf16*)embed)[threadIdx.x + i * 256];
    ss += t * t;
  }
  ss = wsum(ss);
  __shared__ float red[4];
  const int wv = threadIdx.x >> 6, lane = threadIdx.x & 63;
  if (lane == 0) red[wv] = ss;
  __syncthreads();
  if (threadIdx.x == 0) {
    const float tot = red[0] + red[1] + red[2] + red[3];
    flag[0] = (tot < 1e6f) ? 1 : 0;   // NaN fails the compare -> 0
  }
}

// ---------------- scalars -> f32 workspace ----------------
// layout: [0,64)=sw, [64,128)=sr, [128,192)=sO, 192=sE, 193=sF
__global__ __launch_bounds__(256) void scal_kernel(const void* sE, const void* sF,
                                                   const void* sw, const void* sr,
                                                   const void* sO,
                                                   const int* __restrict__ flagp,
                                                   float* __restrict__ scal) {
  const int bf = flagp[0];
  const int i = threadIdx.x;
  if (i < 64)        scal[i] = rdv(sw, i, bf);
  else if (i < 128)  scal[i] = rdv(sr, i - 64, bf);
  else if (i < 192)  scal[i] = rdv(sO, i - 128, bf);
  else if (i == 192) scal[i] = rdv(sE, 0, bf);
  else if (i == 193) scal[i] = rdv(sF, 0, bf);
}

// ---------------- weights -> bf16 workspace ----------------
__global__ __launch_bounds__(256) void wconv_kernel(const void* __restrict__ src,
                                                    bf16* __restrict__ dst,
                                                    const int* __restrict__ flagp,
                                                    int n) {
  const int bf = flagp[0];
  const int base = blockIdx.x * 1024 + threadIdx.x;
#pragma unroll
  for (int j = 0; j < 4; ++j) {
    const int i = base + j * 256;
    if (i < n) dst[i] = (bf16)rdv(src, i, bf);
  }
}

// ---------------- W_norm: row-normalize embed -> bf16 ----------------
__global__ __launch_bounds__(256) void wnorm_kernel(const void* __restrict__ embed,
                                                    const int* __restrict__ flagp,
                                                    bf16* __restrict__ Wn) {
  const int bf = flagp[0];
  const size_t row = blockIdx.x;
  bf16* o = Wn + row * DE;
  float v[4]; float ss = 0.f;
#pragma unroll
  for (int i = 0; i < 4; ++i) {
    v[i] = rdv(embed, row * DE + threadIdx.x + i * 256, bf);
    ss += v[i] * v[i];
  }
  ss = wsum(ss);
  __shared__ float red[4];
  const int wv = threadIdx.x >> 6, lane = threadIdx.x & 63;
  if (lane == 0) red[wv] = ss;
  __syncthreads();
  const float tot = red[0] + red[1] + red[2] + red[3];
  const float inv = 1.f / fmaxf(sqrtf(tot), 1e-12f);
#pragma unroll
  for (int i = 0; i < 4; ++i) o[threadIdx.x + i * 256] = (bf16)(v[i] * inv);
}

// ---------------- gather: x = W_norm[ids] * exp(s_E) ----------------
__global__ __launch_bounds__(256) void gather_kernel(const int* __restrict__ ids,
                                                     const bf16* __restrict__ Wn,
                                                     const float* __restrict__ sEf,
                                                     float* __restrict__ x,
                                                     bf16* __restrict__ xb) {
  const int row = blockIdx.x;
  const int id = ids[row];
  const float sc = expf(sEf[0]);
  const bf16* src = Wn + (size_t)id * DE;
  const size_t base = (size_t)row * DE;
#pragma unroll
  for (int i = 0; i < 4; ++i) {
    const int c = threadIdx.x + i * 256;
    const float v = (float)src[c] * sc;
    x[base + c] = v;
    xb[base + c] = (bf16)v;
  }
}

// ---------------- gemm_bt: C[M,N] = A[M,K] @ Bt[N,K]^T ----------------
// 128x128 tile, BK=32, mfma 16x16x32 bf16, global_load_lds width 16 (m97 pattern)
template<bool ACCUM, bool FINAL>
__global__ __launch_bounds__(256)
void gemm_bt_kernel(const bf16* __restrict__ A, const bf16* __restrict__ Bt,
                    float* __restrict__ C, bf16* __restrict__ Cb,
                    void* __restrict__ outp, const float* __restrict__ scal,
                    const int* __restrict__ flagp, int N, int K) {
  __shared__ __align__(16) bf16 As[128 * 32];
  __shared__ __align__(16) bf16 Bs[128 * 32];
  const int tid  = threadIdx.x;
  const int wave = tid >> 6;
  const int lane = tid & 63;
  const int m_blk = blockIdx.y * 128;
  const int n_blk = blockIdx.x * 128;
  const int wm = (wave >> 1) * 64;
  const int wn = (wave & 1) * 64;
  const int l16 = lane & 15;
  const int l4  = lane >> 4;

  f32x4 acc[4][4] = {};

  const int rs = lane >> 2;          // row within the 16-row group
  const int cs = (lane & 3) * 8;     // k-element offset (8 bf16 = 16B)
  const bf16* Ag0 = A  + (size_t)(m_blk + wave * 16       + rs) * K + cs;
  const bf16* Ag1 = A  + (size_t)(m_blk + (wave + 4) * 16 + rs) * K + cs;
  const bf16* Bg0 = Bt + (size_t)(n_blk + wave * 16       + rs) * K + cs;
  const bf16* Bg1 = Bt + (size_t)(n_blk + (wave + 4) * 16 + rs) * K + cs;
  bf16* As0 = As + wave * 512;       bf16* As1 = As + (wave + 4) * 512;
  bf16* Bs0 = Bs + wave * 512;       bf16* Bs1 = Bs + (wave + 4) * 512;

  for (int kk = 0; kk < K; kk += 32) {
    __syncthreads();                       // all reads of previous tile done
    async16(Ag0, As0); async16(Ag1, As1);
    async16(Bg0, Bs0); async16(Bg1, Bs1);
    Ag0 += 32; Ag1 += 32; Bg0 += 32; Bg1 += 32;
    __syncthreads();                       // drains vmcnt before barrier
    bf16x8 af[4], bfr[4];
#pragma unroll
    for (int i = 0; i < 4; ++i)
      af[i]  = *reinterpret_cast<const bf16x8*>(&As[(wm + i * 16 + l16) * 32 + l4 * 8]);
#pragma unroll
    for (int j = 0; j < 4; ++j)
      bfr[j] = *reinterpret_cast<const bf16x8*>(&Bs[(wn + j * 16 + l16) * 32 + l4 * 8]);
#pragma unroll
    for (int i = 0; i < 4; ++i)
#pragma unroll
      for (int j = 0; j < 4; ++j)
        acc[i][j] = __builtin_amdgcn_mfma_f32_16x16x32_bf16(af[i], bfr[j], acc[i][j], 0, 0, 0);
  }

  float scale = 1.0f;
  int bf = 0;
  if constexpr (FINAL) { scale = expf(scal[0]); bf = flagp[0]; }
#pragma unroll
  for (int i = 0; i < 4; ++i) {
    const int row0 = m_blk + wm + i * 16 + l4 * 4;
#pragma unroll
    for (int j = 0; j < 4; ++j) {
      const int col = n_blk + wn + j * 16 + l16;
#pragma unroll
      for (int r2 = 0; r2 < 4; ++r2) {
        const size_t idx = (size_t)(row0 + r2) * N + col;
        float val = acc[i][j][r2] * scale;
        if constexpr (FINAL) {
          if (bf) ((bf16*)outp)[idx] = (bf16)val;
          else    ((float*)outp)[idx] = val;
        } else if constexpr (ACCUM) {
          val += C[idx];
          C[idx]  = val;
          Cb[idx] = (bf16)val;
        } else {
          C[idx] = val;
        }
      }
    }
  }
}

// ---------------- prep: normalize q,k,v rows (64) + rotary on dims 0,1 ----------------
__global__ __launch_bounds__(256) void prep_kernel(float* __restrict__ q, float* __restrict__ k,
                                                   float* __restrict__ v,
                                                   const float* __restrict__ swf) {
  const int lane = threadIdx.x & 63;
  const int wid  = blockIdx.x * 4 + (threadIdx.x >> 6);
  const int h = wid & (NH - 1);
  const int row = wid >> 4;
  const int t = row & (TSEQ - 1);
  const size_t off = (size_t)row * DE + h * HD + lane;
  float qv = q[off], kv = k[off], vv = v[off];
  const float qi = 1.f / fmaxf(sqrtf(wsum(qv * qv)), 1e-12f);
  const float ki = 1.f / fmaxf(sqrtf(wsum(kv * kv)), 1e-12f);
  const float vi = 1.f / fmaxf(sqrtf(wsum(vv * vv)), 1e-12f);
  qv *= qi; kv *= ki; vv *= vi;
  const float w = expf(swf[h]) + 1.f;
  const float phi = (w < WTH_F) ? 0.5f * (cosf(PI_F * w / WTH_F) + 1.f) : 0.f;
  const float ang = (float)t * phi / w;
  const float c = cosf(ang), s = sinf(ang);
  const float q0 = __shfl(qv, 0), q1 = __shfl(qv, 1);
  const float k0 = __shfl(kv, 0), k1 = __shfl(kv, 1);
  if (lane == 0)      { qv = q0 * c - q1 * s; kv = k0 * c - k1 * s; }
  else if (lane == 1) { qv = q0 * s + q1 * c; kv = k0 * s + k1 * c; }
  q[off] = qv; k[off] = kv; v[off] = vv;
}

// ---------------- attention: persistent waves, one row + 8 heads per wave ----------------
// lane = dim. Mask table in LDS kills inner-loop cosf; 4-way s-unroll for ILP;
// head set {2i + ((wid^i)&1)} balances the geometric window distribution (~95%).
__global__ __launch_bounds__(256) void attn_kernel(const float* __restrict__ q,
                                                   const float* __restrict__ k,
                                                   const float* __restrict__ v,
                                                   const float* __restrict__ g,
                                                   const float* __restrict__ swf,
                                                   const float* __restrict__ srf,
                                                   const float* __restrict__ sOf,
                                                   bf16* __restrict__ hh) {
  __shared__ float mtab[NH][132];
  for (int i = threadIdx.x; i < NH * 132; i += 256) {
    const int h = i / 132;
    const int d = i - h * 132;
    const float w = expf(swf[h]) + 1.f;
    mtab[h][d] = ((float)d < w) ? 0.5f * (cosf(PI_F * (float)d / w) + 1.f) : 0.f;
  }
  __syncthreads();

  const int lane = threadIdx.x & 63;
  const int wid  = blockIdx.x * 4 + (threadIdx.x >> 6);   // 8192 waves total
  const int row  = wid >> 1;
  const int t    = row & (TSEQ - 1);
  const size_t rbase = (size_t)row * DE;
  const size_t seq0  = (size_t)(row - t) * DE;            // start row of this sequence

#pragma unroll 1
  for (int i = 0; i < 8; ++i) {
    const int h = 2 * i + ((wid ^ i) & 1);
    const float w  = expf(swf[h]) + 1.f;
    const float r  = expf(srf[h]) + 1.f;
    const float so = expf(sOf[h]);
    const float ar = 1.f - r;
    const int smin = max(0, t - (int)floorf(w));
    const int n = t - smin + 1;
    const size_t hoff = (size_t)h * HD + lane;
    const float qd = q[rbase + hoff];
    const float* kp = k + seq0 + (size_t)smin * DE + hoff;
    const float* vp = v + seq0 + (size_t)smin * DE + hoff;
    const float* mrow = &mtab[h][0];

    float acc = 0.f;
    int d = n - 1;            // mask index t - s for the first s
    int j = 0;
    for (; j + 4 <= n; j += 4) {
      const float k0 = kp[0], k1 = kp[DE], k2 = kp[2 * DE], k3 = kp[3 * DE];
      const float v0 = vp[0], v1 = vp[DE], v2 = vp[2 * DE], v3 = vp[3 * DE];
      kp += 4 * DE; vp += 4 * DE;
      float s0 = qd * k0, s1 = qd * k1, s2 = qd * k2, s3 = qd * k3;
      red4(s0, s1, s2, s3);
      const float z0 = fmaxf(fmaf(r, s0, ar), 0.f);
      const float z1 = fmaxf(fmaf(r, s1, ar), 0.f);
      const float z2 = fmaxf(fmaf(r, s2, ar), 0.f);
      const float z3 = fmaxf(fmaf(r, s3, ar), 0.f);
      acc = fmaf(z0 * z0 * mrow[d],     v0, acc);
      acc = fmaf(z1 * z1 * mrow[d - 1], v1, acc);
      acc = fmaf(z2 * z2 * mrow[d - 2], v2, acc);
      acc = fmaf(z3 * z3 * mrow[d - 3], v3, acc);
      d -= 4;
    }
    for (; j < n; ++j) {
      const float kk = kp[0], vv = vp[0];
      kp += DE; vp += DE;
      float s0 = red1(qd * kk);
      const float z = fmaxf(fmaf(r, s0, ar), 0.f);
      acc = fmaf(z * z * mrow[d], vv, acc);
      d -= 1;
    }

    const float hn = fmaxf(sqrtf(red1(acc * acc)), 1e-8f);
    const float u = tanhf(hn) / hn * acc;
    const float gv = g[rbase + hoff];
    const float ghat = tanhf(gv / (1.f + expf(-gv)));
    hh[rbase + hoff] = (bf16)(u * ghat * so);
  }
}

// ---------------- orchestration ----------------
extern "C" void kernel_launch(void* const* d_in, const int* in_sizes, int n_in,
                              void* d_out, int out_size, void* d_ws, size_t ws_size,
                              hipStream_t stream) {
  const int*  ids   = (const int*) d_in[0];
  const void* embed = d_in[1];
  const void* sE    = d_in[2];
  const void* sF    = d_in[3];
  const void* Wq    = d_in[4];
  const void* Wk    = d_in[5];
  const void* Wv    = d_in[6];
  const void* Wg    = d_in[7];
  const void* Wo    = d_in[8];
  const void* sw    = d_in[9];
  const void* sr    = d_in[10];
  const void* sO    = d_in[11];

  char* p = (char*)d_ws;
  auto take = [&](size_t bytes) { char* r = p; p += (bytes + 255) & ~255ull; return r; };
  int*   flag = (int*)  take(4);
  float* scal = (float*)take(194 * sizeof(float));
  const size_t WSZ = (size_t)NL * DE * DE;   // 4,194,304
  bf16* Wqb = (bf16*)take(WSZ * sizeof(bf16));
  bf16* Wkb = (bf16*)take(WSZ * sizeof(bf16));
  bf16* Wvb = (bf16*)take(WSZ * sizeof(bf16));
  bf16* Wgb = (bf16*)take(WSZ * sizeof(bf16));
  bf16* Wob = (bf16*)take(WSZ * sizeof(bf16));
  bf16*  Wn = (bf16*) take((size_t)VOCAB * DE * sizeof(bf16));
  float* x  = (float*)take((size_t)MR * DE * sizeof(float));
  bf16*  xb = (bf16*) take((size_t)MR * DE * sizeof(bf16));
  float* q  = (float*)take((size_t)MR * DE * sizeof(float));
  float* k  = (float*)take((size_t)MR * DE * sizeof(float));
  float* v  = (float*)take((size_t)MR * DE * sizeof(float));
  float* g  = (float*)take((size_t)MR * DE * sizeof(float));
  bf16*  hh = (bf16*) take((size_t)MR * DE * sizeof(bf16));

  detect_kernel<<<1, 256, 0, stream>>>(embed, flag);
  scal_kernel<<<1, 256, 0, stream>>>(sE, sF, sw, sr, sO, flag, scal);
  const int wgrid = (int)(WSZ / 1024);
  wconv_kernel<<<wgrid, 256, 0, stream>>>(Wq, Wqb, flag, (int)WSZ);
  wconv_kernel<<<wgrid, 256, 0, stream>>>(Wk, Wkb, flag, (int)WSZ);
  wconv_kernel<<<wgrid, 256, 0, stream>>>(Wv, Wvb, flag, (int)WSZ);
  wconv_kernel<<<wgrid, 256, 0, stream>>>(Wg, Wgb, flag, (int)WSZ);
  wconv_kernel<<<wgrid, 256, 0, stream>>>(Wo, Wob, flag, (int)WSZ);
  wnorm_kernel<<<VOCAB, 256, 0, stream>>>(embed, flag, Wn);
  gather_kernel<<<MR, 256, 0, stream>>>(ids, Wn, scal + 192, x, xb);

  for (int l = 0; l < NL; ++l) {
    const size_t wofs = (size_t)l * DE * DE;
    dim3 gproj(DE / 128, MR / 128);
    gemm_bt_kernel<false, false><<<gproj, 256, 0, stream>>>(xb, Wqb + wofs, q, nullptr, nullptr, nullptr, nullptr, DE, DE);
    gemm_bt_kernel<false, false><<<gproj, 256, 0, stream>>>(xb, Wkb + wofs, k, nullptr, nullptr, nullptr, nullptr, DE, DE);
    gemm_bt_kernel<false, false><<<gproj, 256, 0, stream>>>(xb, Wvb + wofs, v, nullptr, nullptr, nullptr, nullptr, DE, DE);
    gemm_bt_kernel<false, false><<<gproj, 256, 0, stream>>>(xb, Wgb + wofs, g, nullptr, nullptr, nullptr, nullptr, DE, DE);
    prep_kernel<<<MR * NH / 4, 256, 0, stream>>>(q, k, v, scal + l * NH);
    attn_kernel<<<MR * NH / 32, 256, 0, stream>>>(q, k, v, g,
                                                  scal + l * NH, scal + 64 + l * NH, scal + 128 + l * NH, hh);
    gemm_bt_kernel<true, false><<<gproj, 256, 0, stream>>>(hh, Wob + wofs, x, xb, nullptr, nullptr, nullptr, DE, DE);
  }

  gemm_bt_kernel<false, true><<<dim3(VOCAB / 128, MR / 128), 256, 0, stream>>>(
      xb, Wn, nullptr, nullptr, d_out, scal + 193, flag, VOCAB, DE);
}

// Round 2
// 2118.335 us; speedup vs baseline: 1.7733x; 1.0560x over previous
//
#include <hip/hip_runtime.h>
#include <hip/hip_bf16.h>
#include <math.h>

typedef __hip_bfloat16 bf16;
typedef __bf16 bf16x8 __attribute__((ext_vector_type(8)));
typedef float f32x4 __attribute__((ext_vector_type(4)));

#define VOCAB 32000
#define DE 1024
#define NH 16
#define HD 64
#define NL 4
#define TSEQ 2048
#define MR 4096          // B*T rows
#define WTH_F 128.0f
#define PI_F 3.14159265358979f

// ---- cheap 64-lane butterfly primitives ----
// xor1/xor2 via DPP quad_perm, xor4-equiv via ROW_HALF_MIRROR (i^7), xor8-equiv
// via ROW_MIRROR (i^15) -- valid because after stages 1,2 all lanes of a
// 4-group (resp. 8-group) hold bit-identical partials, so adding lane i^7
// (== group i^4's value) is exact. xor16 via ds_swizzle, xor32 via shfl.
template<int CTRL>
__device__ __forceinline__ float dpp_f(float x) {
  return __int_as_float(__builtin_amdgcn_update_dpp(
      0, __float_as_int(x), CTRL, 0xF, 0xF, false));
}
template<int PAT>
__device__ __forceinline__ float swz(float x) {
  return __int_as_float(__builtin_amdgcn_ds_swizzle(__float_as_int(x), PAT));
}

__device__ __forceinline__ float wsum(float a) {
  a += dpp_f<0xB1>(a);       // xor 1  (quad_perm [1,0,3,2])
  a += dpp_f<0x4E>(a);       // xor 2  (quad_perm [2,3,0,1])
  a += dpp_f<0x141>(a);      // row_half_mirror == lane i^7 -> xor4 stage
  a += dpp_f<0x140>(a);      // row_mirror      == lane i^15 -> xor8 stage
  a += swz<0x401F>(a);       // xor 16
  a += __shfl_xor(a, 32);    // xor 32
  return a;
}

__device__ __forceinline__ float red1(float a) { return wsum(a); }

__device__ __forceinline__ void red4(float& a, float& b, float& c, float& d) {
  a += dpp_f<0xB1>(a);  b += dpp_f<0xB1>(b);  c += dpp_f<0xB1>(c);  d += dpp_f<0xB1>(d);
  a += dpp_f<0x4E>(a);  b += dpp_f<0x4E>(b);  c += dpp_f<0x4E>(c);  d += dpp_f<0x4E>(d);
  a += dpp_f<0x141>(a); b += dpp_f<0x141>(b); c += dpp_f<0x141>(c); d += dpp_f<0x141>(d);
  a += dpp_f<0x140>(a); b += dpp_f<0x140>(b); c += dpp_f<0x140>(c); d += dpp_f<0x140>(d);
  a += swz<0x401F>(a);  b += swz<0x401F>(b);  c += swz<0x401F>(c);  d += swz<0x401F>(d);
  a += __shfl_xor(a, 32); b += __shfl_xor(b, 32); c += __shfl_xor(c, 32); d += __shfl_xor(d, 32);
}

__device__ __forceinline__ void async16(const bf16* g, bf16* l) {
  __builtin_amdgcn_global_load_lds(
      (const __attribute__((address_space(1))) void*)g,
      (__attribute__((address_space(3))) void*)l, 16, 0, 0);
}

// dual-dtype element read: bf=1 -> bf16, bf=0 -> fp32
__device__ __forceinline__ float rdv(const void* p, size_t i, int bf) {
  return bf ? (float)((const bf16*)p)[i] : ((const float*)p)[i];
}

// ---------------- detect input dtype from embed row 0 ----------------
__global__ __launch_bounds__(256) void detect_kernel(const void* __restrict__ embed,
                                                     int* __restrict__ flag) {
  float ss = 0.f;
#pragma unroll
  for (int i = 0; i < 4; ++i) {
    const float t = (float)((const bf16*)embed)[threadIdx.x + i * 256];
    ss += t * t;
  }
  ss = wsum(ss);
  __shared__ float red[4];
  const int wv = threadIdx.x >> 6, lane = threadIdx.x & 63;
  if (lane == 0) red[wv] = ss;
  __syncthreads();
  if (threadIdx.x == 0) {
    const float tot = red[0] + red[1] + red[2] + red[3];
    flag[0] = (tot < 1e6f) ? 1 : 0;   // NaN fails the compare -> 0
  }
}

// ---------------- scalars -> f32 workspace ----------------
// layout: [0,64)=sw, [64,128)=sr, [128,192)=sO, 192=sE, 193=sF
__global__ __launch_bounds__(256) void scal_kernel(const void* sE, const void* sF,
                                                   const void* sw, const void* sr,
                                                   const void* sO,
                                                   const int* __restrict__ flagp,
                                                   float* __restrict__ scal) {
  const int bf = flagp[0];
  const int i = threadIdx.x;
  if (i < 64)        scal[i] = rdv(sw, i, bf);
  else if (i < 128)  scal[i] = rdv(sr, i - 64, bf);
  else if (i < 192)  scal[i] = rdv(sO, i - 128, bf);
  else if (i == 192) scal[i] = rdv(sE, 0, bf);
  else if (i == 193) scal[i] = rdv(sF, 0, bf);
}

// ---------------- weights -> bf16 workspace ----------------
__global__ __launch_bounds__(256) void wconv_kernel(const void* __restrict__ src,
                                                    bf16* __restrict__ dst,
                                                    const int* __restrict__ flagp,
                                                    int n) {
  const int bf = flagp[0];
  const int base = blockIdx.x * 1024 + threadIdx.x;
#pragma unroll
  for (int j = 0; j < 4; ++j) {
    const int i = base + j * 256;
    if (i < n) dst[i] = (bf16)rdv(src, i, bf);
  }
}

// ---------------- W_norm: row-normalize embed -> bf16 ----------------
__global__ __launch_bounds__(256) void wnorm_kernel(const void* __restrict__ embed,
                                                    const int* __restrict__ flagp,
                                                    bf16* __restrict__ Wn) {
  const int bf = flagp[0];
  const size_t row = blockIdx.x;
  bf16* o = Wn + row * DE;
  float v[4]; float ss = 0.f;
#pragma unroll
  for (int i = 0; i < 4; ++i) {
    v[i] = rdv(embed, row * DE + threadIdx.x + i * 256, bf);
    ss += v[i] * v[i];
  }
  ss = wsum(ss);
  __shared__ float red[4];
  const int wv = threadIdx.x >> 6, lane = threadIdx.x & 63;
  if (lane == 0) red[wv] = ss;
  __syncthreads();
  const float tot = red[0] + red[1] + red[2] + red[3];
  const float inv = 1.f / fmaxf(sqrtf(tot), 1e-12f);
#pragma unroll
  for (int i = 0; i < 4; ++i) o[threadIdx.x + i * 256] = (bf16)(v[i] * inv);
}

// ---------------- gather: x = W_norm[ids] * exp(s_E) ----------------
__global__ __launch_bounds__(256) void gather_kernel(const int* __restrict__ ids,
                                                     const bf16* __restrict__ Wn,
                                                     const float* __restrict__ sEf,
                                                     float* __restrict__ x,
                                                     bf16* __restrict__ xb) {
  const int row = blockIdx.x;
  const int id = ids[row];
  const float sc = expf(sEf[0]);
  const bf16* src = Wn + (size_t)id * DE;
  const size_t base = (size_t)row * DE;
#pragma unroll
  for (int i = 0; i < 4; ++i) {
    const int c = threadIdx.x + i * 256;
    const float v = (float)src[c] * sc;
    x[base + c] = v;
    xb[base + c] = (bf16)v;
  }
}

// ---------------- gemm_bt: C[M,N] = A[M,K] @ Bt[N,K]^T ----------------
// 128x128 tile, BK=32, mfma 16x16x32 bf16, global_load_lds width 16 (m97 pattern)
// XCD-bijective chunked block swizzle (T1/m204): each XCD owns a contiguous
// n-fastest wgid range -> its few A row-strips stay L2-resident while B streams.
template<bool ACCUM, bool FINAL>
__global__ __launch_bounds__(256)
void gemm_bt_kernel(const bf16* __restrict__ A, const bf16* __restrict__ Bt,
                    float* __restrict__ C, bf16* __restrict__ Cb,
                    void* __restrict__ outp, const float* __restrict__ scal,
                    const int* __restrict__ flagp, int N, int K) {
  __shared__ __align__(16) bf16 As[128 * 32];
  __shared__ __align__(16) bf16 Bs[128 * 32];
  const int tid  = threadIdx.x;
  const int wave = tid >> 6;
  const int lane = tid & 63;

  const int gx  = gridDim.x;
  const int nwg = gx * gridDim.y;
  const int bid = blockIdx.y * gx + blockIdx.x;
  const int qq  = nwg >> 3, rr = nwg & 7;
  const int xcd = bid & 7, sub = bid >> 3;
  const int wgid = (xcd < rr ? xcd * (qq + 1) : rr * (qq + 1) + (xcd - rr) * qq) + sub;
  const int m_blk = (wgid / gx) * 128;
  const int n_blk = (wgid % gx) * 128;

  const int wm = (wave >> 1) * 64;
  const int wn = (wave & 1) * 64;
  const int l16 = lane & 15;
  const int l4  = lane >> 4;

  f32x4 acc[4][4] = {};

  const int rs = lane >> 2;          // row within the 16-row group
  const int cs = (lane & 3) * 8;     // k-element offset (8 bf16 = 16B)
  const bf16* Ag0 = A  + (size_t)(m_blk + wave * 16       + rs) * K + cs;
  const bf16* Ag1 = A  + (size_t)(m_blk + (wave + 4) * 16 + rs) * K + cs;
  const bf16* Bg0 = Bt + (size_t)(n_blk + wave * 16       + rs) * K + cs;
  const bf16* Bg1 = Bt + (size_t)(n_blk + (wave + 4) * 16 + rs) * K + cs;
  bf16* As0 = As + wave * 512;       bf16* As1 = As + (wave + 4) * 512;
  bf16* Bs0 = Bs + wave * 512;       bf16* Bs1 = Bs + (wave + 4) * 512;

  for (int kk = 0; kk < K; kk += 32) {
    __syncthreads();                       // all reads of previous tile done
    async16(Ag0, As0); async16(Ag1, As1);
    async16(Bg0, Bs0); async16(Bg1, Bs1);
    Ag0 += 32; Ag1 += 32; Bg0 += 32; Bg1 += 32;
    __syncthreads();                       // drains vmcnt before barrier
    bf16x8 af[4], bfr[4];
#pragma unroll
    for (int i = 0; i < 4; ++i)
      af[i]  = *reinterpret_cast<const bf16x8*>(&As[(wm + i * 16 + l16) * 32 + l4 * 8]);
#pragma unroll
    for (int j = 0; j < 4; ++j)
      bfr[j] = *reinterpret_cast<const bf16x8*>(&Bs[(wn + j * 16 + l16) * 32 + l4 * 8]);
#pragma unroll
    for (int i = 0; i < 4; ++i)
#pragma unroll
      for (int j = 0; j < 4; ++j)
        acc[i][j] = __builtin_amdgcn_mfma_f32_16x16x32_bf16(af[i], bfr[j], acc[i][j], 0, 0, 0);
  }

  float scale = 1.0f;
  int bf = 0;
  if constexpr (FINAL) { scale = expf(scal[0]); bf = flagp[0]; }
#pragma unroll
  for (int i = 0; i < 4; ++i) {
    const int row0 = m_blk + wm + i * 16 + l4 * 4;
#pragma unroll
    for (int j = 0; j < 4; ++j) {
      const int col = n_blk + wn + j * 16 + l16;
#pragma unroll
      for (int r2 = 0; r2 < 4; ++r2) {
        const size_t idx = (size_t)(row0 + r2) * N + col;
        float val = acc[i][j][r2] * scale;
        if constexpr (FINAL) {
          if (bf) ((bf16*)outp)[idx] = (bf16)val;
          else    ((float*)outp)[idx] = val;
        } else if constexpr (ACCUM) {
          val += C[idx];
          C[idx]  = val;
          Cb[idx] = (bf16)val;
        } else {
          C[idx] = val;
        }
      }
    }
  }
}

// ---------------- prep: normalize q,k,v rows (64) + rotary on dims 0,1 ----------------
__global__ __launch_bounds__(256) void prep_kernel(float* __restrict__ q, float* __restrict__ k,
                                                   float* __restrict__ v,
                                                   const float* __restrict__ swf) {
  const int lane = threadIdx.x & 63;
  const int wid  = blockIdx.x * 4 + (threadIdx.x >> 6);
  const int h = wid & (NH - 1);
  const int row = wid >> 4;
  const int t = row & (TSEQ - 1);
  const size_t off = (size_t)row * DE + h * HD + lane;
  float qv = q[off], kv = k[off], vv = v[off];
  const float qi = 1.f / fmaxf(sqrtf(wsum(qv * qv)), 1e-12f);
  const float ki = 1.f / fmaxf(sqrtf(wsum(kv * kv)), 1e-12f);
  const float vi = 1.f / fmaxf(sqrtf(wsum(vv * vv)), 1e-12f);
  qv *= qi; kv *= ki; vv *= vi;
  const float w = expf(swf[h]) + 1.f;
  const float phi = (w < WTH_F) ? 0.5f * (cosf(PI_F * w / WTH_F) + 1.f) : 0.f;
  const float ang = (float)t * phi / w;
  const float c = cosf(ang), s = sinf(ang);
  const float q0 = __shfl(qv, 0), q1 = __shfl(qv, 1);
  const float k0 = __shfl(kv, 0), k1 = __shfl(kv, 1);
  if (lane == 0)      { qv = q0 * c - q1 * s; kv = k0 * c - k1 * s; }
  else if (lane == 1) { qv = q0 * s + q1 * c; kv = k0 * s + k1 * c; }
  q[off] = qv; k[off] = kv; v[off] = vv;
}

// ---------------- attention: persistent waves, one row + 8 heads per wave ----------------
// lane = dim. Mask table in LDS kills inner-loop cosf; 4-way s-unroll for ILP;
// head set {2i + ((wid^i)&1)} balances the geometric window distribution (~95%).
__global__ __launch_bounds__(256) void attn_kernel(const float* __restrict__ q,
                                                   const float* __restrict__ k,
                                                   const float* __restrict__ v,
                                                   const float* __restrict__ g,
                                                   const float* __restrict__ swf,
                                                   const float* __restrict__ srf,
                                                   const float* __restrict__ sOf,
                                                   bf16* __restrict__ hh) {
  __shared__ float mtab[NH][132];
  for (int i = threadIdx.x; i < NH * 132; i += 256) {
    const int h = i / 132;
    const int d = i - h * 132;
    const float w = expf(swf[h]) + 1.f;
    mtab[h][d] = ((float)d < w) ? 0.5f * (cosf(PI_F * (float)d / w) + 1.f) : 0.f;
  }
  __syncthreads();

  const int lane = threadIdx.x & 63;
  const int wid  = blockIdx.x * 4 + (threadIdx.x >> 6);   // 8192 waves total
  const int row  = wid >> 1;
  const int t    = row & (TSEQ - 1);
  const size_t rbase = (size_t)row * DE;
  const size_t seq0  = (size_t)(row - t) * DE;            // start row of this sequence

#pragma unroll 1
  for (int i = 0; i < 8; ++i) {
    const int h = 2 * i + ((wid ^ i) & 1);
    const float w  = expf(swf[h]) + 1.f;
    const float r  = expf(srf[h]) + 1.f;
    const float so = expf(sOf[h]);
    const float ar = 1.f - r;
    const int smin = max(0, t - (int)floorf(w));
    const int n = t - smin + 1;
    const size_t hoff = (size_t)h * HD + lane;
    const float qd = q[rbase + hoff];
    const float* kp = k + seq0 + (size_t)smin * DE + hoff;
    const float* vp = v + seq0 + (size_t)smin * DE + hoff;
    const float* mrow = &mtab[h][0];

    float acc = 0.f;
    int d = n - 1;            // mask index t - s for the first s
    int j = 0;
    for (; j + 4 <= n; j += 4) {
      const float k0 = kp[0], k1 = kp[DE], k2 = kp[2 * DE], k3 = kp[3 * DE];
      const float v0 = vp[0], v1 = vp[DE], v2 = vp[2 * DE], v3 = vp[3 * DE];
      kp += 4 * DE; vp += 4 * DE;
      float s0 = qd * k0, s1 = qd * k1, s2 = qd * k2, s3 = qd * k3;
      red4(s0, s1, s2, s3);
      const float z0 = fmaxf(fmaf(r, s0, ar), 0.f);
      const float z1 = fmaxf(fmaf(r, s1, ar), 0.f);
      const float z2 = fmaxf(fmaf(r, s2, ar), 0.f);
      const float z3 = fmaxf(fmaf(r, s3, ar), 0.f);
      acc = fmaf(z0 * z0 * mrow[d],     v0, acc);
      acc = fmaf(z1 * z1 * mrow[d - 1], v1, acc);
      acc = fmaf(z2 * z2 * mrow[d - 2], v2, acc);
      acc = fmaf(z3 * z3 * mrow[d - 3], v3, acc);
      d -= 4;
    }
    for (; j < n; ++j) {
      const float kk = kp[0], vv = vp[0];
      kp += DE; vp += DE;
      float s0 = red1(qd * kk);
      const float z = fmaxf(fmaf(r, s0, ar), 0.f);
      acc = fmaf(z * z * mrow[d], vv, acc);
      d -= 1;
    }

    const float hn = fmaxf(sqrtf(red1(acc * acc)), 1e-8f);
    const float u = tanhf(hn) / hn * acc;
    const float gv = g[rbase + hoff];
    const float ghat = tanhf(gv / (1.f + expf(-gv)));
    hh[rbase + hoff] = (bf16)(u * ghat * so);
  }
}

// ---------------- orchestration ----------------
extern "C" void kernel_launch(void* const* d_in, const int* in_sizes, int n_in,
                              void* d_out, int out_size, void* d_ws, size_t ws_size,
                              hipStream_t stream) {
  const int*  ids   = (const int*) d_in[0];
  const void* embed = d_in[1];
  const void* sE    = d_in[2];
  const void* sF    = d_in[3];
  const void* Wq    = d_in[4];
  const void* Wk    = d_in[5];
  const void* Wv    = d_in[6];
  const void* Wg    = d_in[7];
  const void* Wo    = d_in[8];
  const void* sw    = d_in[9];
  const void* sr    = d_in[10];
  const void* sO    = d_in[11];

  char* p = (char*)d_ws;
  auto take = [&](size_t bytes) { char* r = p; p += (bytes + 255) & ~255ull; return r; };
  int*   flag = (int*)  take(4);
  float* scal = (float*)take(194 * sizeof(float));
  const size_t WSZ = (size_t)NL * DE * DE;   // 4,194,304
  bf16* Wqb = (bf16*)take(WSZ * sizeof(bf16));
  bf16* Wkb = (bf16*)take(WSZ * sizeof(bf16));
  bf16* Wvb = (bf16*)take(WSZ * sizeof(bf16));
  bf16* Wgb = (bf16*)take(WSZ * sizeof(bf16));
  bf16* Wob = (bf16*)take(WSZ * sizeof(bf16));
  bf16*  Wn = (bf16*) take((size_t)VOCAB * DE * sizeof(bf16));
  float* x  = (float*)take((size_t)MR * DE * sizeof(float));
  bf16*  xb = (bf16*) take((size_t)MR * DE * sizeof(bf16));
  float* q  = (float*)take((size_t)MR * DE * sizeof(float));
  float* k  = (float*)take((size_t)MR * DE * sizeof(float));
  float* v  = (float*)take((size_t)MR * DE * sizeof(float));
  float* g  = (float*)take((size_t)MR * DE * sizeof(float));
  bf16*  hh = (bf16*) take((size_t)MR * DE * sizeof(bf16));

  detect_kernel<<<1, 256, 0, stream>>>(embed, flag);
  scal_kernel<<<1, 256, 0, stream>>>(sE, sF, sw, sr, sO, flag, scal);
  const int wgrid = (int)(WSZ / 1024);
  wconv_kernel<<<wgrid, 256, 0, stream>>>(Wq, Wqb, flag, (int)WSZ);
  wconv_kernel<<<wgrid, 256, 0, stream>>>(Wk, Wkb, flag, (int)WSZ);
  wconv_kernel<<<wgrid, 256, 0, stream>>>(Wv, Wvb, flag, (int)WSZ);
  wconv_kernel<<<wgrid, 256, 0, stream>>>(Wg, Wgb, flag, (int)WSZ);
  wconv_kernel<<<wgrid, 256, 0, stream>>>(Wo, Wob, flag, (int)WSZ);
  wnorm_kernel<<<VOCAB, 256, 0, stream>>>(embed, flag, Wn);
  gather_kernel<<<MR, 256, 0, stream>>>(ids, Wn, scal + 192, x, xb);

  for (int l = 0; l < NL; ++l) {
    const size_t wofs = (size_t)l * DE * DE;
    dim3 gproj(DE / 128, MR / 128);
    gemm_bt_kernel<false, false><<<gproj, 256, 0, stream>>>(xb, Wqb + wofs, q, nullptr, nullptr, nullptr, nullptr, DE, DE);
    gemm_bt_kernel<false, false><<<gproj, 256, 0, stream>>>(xb, Wkb + wofs, k, nullptr, nullptr, nullptr, nullptr, DE, DE);
    gemm_bt_kernel<false, false><<<gproj, 256, 0, stream>>>(xb, Wvb + wofs, v, nullptr, nullptr, nullptr, nullptr, DE, DE);
    gemm_bt_kernel<false, false><<<gproj, 256, 0, stream>>>(xb, Wgb + wofs, g, nullptr, nullptr, nullptr, nullptr, DE, DE);
    prep_kernel<<<MR * NH / 4, 256, 0, stream>>>(q, k, v, scal + l * NH);
    attn_kernel<<<MR * NH / 32, 256, 0, stream>>>(q, k, v, g,
                                                  scal + l * NH, scal + 64 + l * NH, scal + 128 + l * NH, hh);
    gemm_bt_kernel<true, false><<<gproj, 256, 0, stream>>>(hh, Wob + wofs, x, xb, nullptr, nullptr, nullptr, DE, DE);
  }

  gemm_bt_kernel<false, true><<<dim3(VOCAB / 128, MR / 128), 256, 0, stream>>>(
      xb, Wn, nullptr, nullptr, d_out, scal + 193, flag, VOCAB, DE);
}